// Round 6
// baseline (612.730 us; speedup 1.0000x reference)
//
#include <hip/hip_runtime.h>
#include <hip/hip_bf16.h>
#include <hip/hip_cooperative_groups.h>

namespace cg = cooperative_groups;

// Problem constants
#define Bq 2
#define Tq 2048
#define Cq 1024
#define Hq 16
#define HKVq 4
#define HDq 64
#define Gq 4
#define WSq 1024
#define GATE_CHq 32

typedef __attribute__((ext_vector_type(8))) short short8;   // 8 bf16 (4 VGPRs)
typedef __attribute__((ext_vector_type(4))) float f32x4;    // MFMA C/D frag
typedef __attribute__((ext_vector_type(16))) float f32x16;  // 32x32 MFMA C/D
typedef __attribute__((ext_vector_type(2))) unsigned int u32x2;
typedef unsigned int u32;
typedef unsigned short u16;

#if __has_builtin(__builtin_amdgcn_exp2f)
#define EXP2(x) __builtin_amdgcn_exp2f(x)
#else
#define EXP2(x) exp2f(x)
#endif

__device__ __forceinline__ u16 f2bf(float f) {
  u32 u = __float_as_uint(f);
  u32 r = (u + 0x7FFFu + ((u >> 16) & 1u)) >> 16;  // RNE
  return (u16)r;
}

__device__ __forceinline__ void gl_lds16(const u16* g, u16* l) {
  __builtin_amdgcn_global_load_lds(
      (const u32 __attribute__((address_space(1)))*)g,
      (u32 __attribute__((address_space(3)))*)l, 16, 0, 0);
}

#define CEXP 0.18033688011112042f   // 0.125 * log2(e)
#define CEXP8 1.4426950408889634f   // 8 * 0.125 * log2(e)

// attn inner tile (32x32x16 MFMA, swapped operands; in-register P via
// permlane32_swap). Ks/Vts are the CURRENT K/V LDS buffers.
template <bool MASK>
__device__ __forceinline__ void attn_tile32(
    int k0, int q0, int l31, int hl, const u16* __restrict__ Ks,
    const u16* __restrict__ Vts, const short8 (&QB)[4], f32x16& O0, f32x16& O1,
    float& lsum) {
  const int qpos = q0 + l31;
#pragma unroll
  for (int c = 0; c < 4; c++) {
    const int key = c * 32 + l31;
    f32x16 S;
#pragma unroll
    for (int i = 0; i < 16; i++) S[i] = 0.f;
    __builtin_amdgcn_s_setprio(1);
#pragma unroll
    for (int s = 0; s < 4; s++) {
      short8 kf = *(const short8*)&Ks[key * 64 + (((s * 2 + hl) ^ (key & 7)) * 8)];
      S = __builtin_amdgcn_mfma_f32_32x32x16_bf16(kf, QB[s], S, 0, 0, 0);
    }
    __builtin_amdgcn_s_setprio(0);
    const int kb = k0 + c * 32 + 4 * hl;
    float p[16];
    float la0 = 0.f, la1 = 0.f;
#pragma unroll
    for (int r = 0; r < 16; r++) {
      float sv = S[r];
      if (MASK) {
        int kpos = kb + (r & 3) + 8 * (r >> 2);
        u32 diff = (u32)(qpos - kpos);
        sv = (diff < (u32)WSq) ? sv : -1e30f;
      }
      float pv = EXP2(__builtin_fmaf(sv, CEXP, -CEXP8));
      if (r & 1) la1 += pv; else la0 += pv;
      p[r] = pv;
    }
    lsum += la0 + la1;
    u32 w8[8];
#pragma unroll
    for (int i = 0; i < 8; i++) {
      u32 lo = __float_as_uint(p[2 * i]) + 0x8000u;
      u32 hi = __float_as_uint(p[2 * i + 1]) + 0x8000u;
      w8[i] = __builtin_amdgcn_perm(hi, lo, 0x07060302u);
    }
    u32x2 r02 = __builtin_amdgcn_permlane32_swap(w8[0], w8[2], false, false);
    u32x2 r13 = __builtin_amdgcn_permlane32_swap(w8[1], w8[3], false, false);
    u32x2 r46 = __builtin_amdgcn_permlane32_swap(w8[4], w8[6], false, false);
    u32x2 r57 = __builtin_amdgcn_permlane32_swap(w8[5], w8[7], false, false);
    union { short8 s8; u32 u[4]; } f0, f1;
    f0.u[0] = r02[0]; f0.u[1] = r13[0]; f0.u[2] = r02[1]; f0.u[3] = r13[1];
    f1.u[0] = r46[0]; f1.u[1] = r57[0]; f1.u[2] = r46[1]; f1.u[3] = r57[1];
    const int d0 = l31, d1 = 32 + l31;
    const int sw = (l31 & 7);
    __builtin_amdgcn_s_setprio(1);
#pragma unroll
    for (int kc = 0; kc < 2; kc++) {
      int grp = c * 4 + kc * 2 + hl;
      short8 v0 = *(const short8*)&Vts[d0 * 128 + ((grp ^ sw) * 8)];
      short8 v1 = *(const short8*)&Vts[d1 * 128 + ((grp ^ sw) * 8)];
      const short8 pf = kc ? f1.s8 : f0.s8;
      O0 = __builtin_amdgcn_mfma_f32_32x32x16_bf16(v0, pf, O0, 0, 0, 0);
      O1 = __builtin_amdgcn_mfma_f32_32x32x16_bf16(v1, pf, O1, 0, 0, 0);
    }
    __builtin_amdgcn_s_setprio(0);
  }
}

// ---------------------------------------------------------------------------
// Single cooperative megakernel: prep -> qkv(+epilogue) -> attn -> proj.
// Explicit agent-scope fences around each grid.sync (cross-XCD L2 safety).
// 512 blocks x 256 thr, 64 KB LDS, 2 blocks/CU.
// ---------------------------------------------------------------------------
__global__ __launch_bounds__(256, 2) void mega(
    const float* __restrict__ x, const float* __restrict__ ve,
    const float* __restrict__ cosp, const float* __restrict__ sinp,
    const float* __restrict__ Wq, const float* __restrict__ Wk,
    const float* __restrict__ Wv, const float* __restrict__ Wproj,
    const float* __restrict__ Wg, u16* __restrict__ xb,
    u16* __restrict__ WqkvT, u16* __restrict__ WprojT, u16* __restrict__ Qb,
    u16* __restrict__ Kb, u16* __restrict__ Vtb, float* __restrict__ gateb,
    float* __restrict__ out) {
  __shared__ __attribute__((aligned(16))) u16 smem[32768];  // 64 KB
  cg::grid_group grid = cg::this_grid();

  const int bid = blockIdx.x;
  const int tid = threadIdx.x;
  const int w = tid >> 6, lane = tid & 63;
  const int quad = lane >> 4, l16 = lane & 15;

  // ===================== phase 0: prep =====================
  for (int vb = bid; vb < 2752; vb += 512) {
    if (vb < 2048) {
      int i = (vb * 256 + tid) * 8;
      float4 a = *(const float4*)(x + i);
      float4 b4 = *(const float4*)(x + i + 4);
      union { short8 v; u16 u[8]; } o;
      o.u[0] = f2bf(a.x); o.u[1] = f2bf(a.y); o.u[2] = f2bf(a.z); o.u[3] = f2bf(a.w);
      o.u[4] = f2bf(b4.x); o.u[5] = f2bf(b4.y); o.u[6] = f2bf(b4.z); o.u[7] = f2bf(b4.w);
      *(short8*)(xb + i) = o.v;
    } else if (vb >= 2688) {
      int p = (vb - 2688) * 256 + tid;   // 0..16383
      int bt = p >> 2, kk = p & 3;
      const float* xr = x + (long)bt * Cq;
      float dot = 0.f;
#pragma unroll
      for (int i = 0; i < GATE_CHq; i++) dot += xr[i] * Wg[i * HKVq + kk];
      gateb[p] = 2.f / (1.f + expf(-dot));
    } else {
      float* tile = (float*)smem;        // [64][65]
      int wb = vb - 2048;                // 0..639
      int obx = wb >> 4;                 // 0..39
      int k0 = (wb & 15) * 64;
      const float* S;
      u16* Dst;
      int N, nb;
      if (obx < 16)      { S = Wq;    N = 1024; nb = obx;      Dst = WqkvT; }
      else if (obx < 20) { S = Wk;    N = 256;  nb = obx - 16; Dst = WqkvT + 1024 * 1024; }
      else if (obx < 24) { S = Wv;    N = 256;  nb = obx - 20; Dst = WqkvT + 1280 * 1024; }
      else               { S = Wproj; N = 1024; nb = obx - 24; Dst = WprojT; }
      int n0 = nb * 64;
#pragma unroll
      for (int i = 0; i < 16; i++) {
        int idx = i * 256 + tid;
        int kl = idx >> 6, nl = idx & 63;
        tile[kl * 65 + nl] = S[(long)(k0 + kl) * N + n0 + nl];
      }
      __syncthreads();
#pragma unroll
      for (int i = 0; i < 16; i++) {
        int idx = i * 256 + tid;
        int nl = idx >> 6, kl = idx & 63;
        Dst[(long)(n0 + nl) * 1024 + k0 + kl] = f2bf(tile[kl * 65 + nl]);
      }
      __syncthreads();
    }
  }
  __threadfence();
  grid.sync();
  __threadfence();

  // ===================== phase 1: qkv GEMM + epilogue =====================
  if (bid < 384) {
    const int bx = bid % 12;
    const int bm0 = (bid / 12) * 128, bn0 = bx * 128;
    const int wm = (w >> 1) * 64, wn = (w & 1) * 64;
    const int K = 1024;
    u16* sA = smem;            // 128x128 bf16, 32 KB
    u16* sB = smem + 16384;    // 128x128 bf16, 32 KB

    f32x4 acc[4][4];
#pragma unroll
    for (int mt = 0; mt < 4; mt++)
#pragma unroll
      for (int nt = 0; nt < 4; nt++) acc[mt][nt] = (f32x4){0.f, 0.f, 0.f, 0.f};

    int goff[8];
#pragma unroll
    for (int i = 0; i < 8; i++) {
      int s = i * 256 + tid;
      int m = s >> 4, gp = s & 15;
      goff[i] = m * K + (gp ^ (m & 7)) * 8;
    }
    const u16* Ab = xb + (long)bm0 * K;
    const u16* Bb = WqkvT + (long)bn0 * K;

    for (int k0 = 0; k0 < K; k0 += 128) {
      __syncthreads();
#pragma unroll
      for (int i = 0; i < 8; i++)
        gl_lds16(Ab + goff[i] + k0, &sA[(i * 256 + w * 64) * 8]);
#pragma unroll
      for (int i = 0; i < 8; i++)
        gl_lds16(Bb + goff[i] + k0, &sB[(i * 256 + w * 64) * 8]);
      __syncthreads();

#pragma unroll
      for (int ks = 0; ks < 4; ks++) {
        short8 af[4], bf[4];
#pragma unroll
        for (int mt = 0; mt < 4; mt++) {
          int ml = wm + mt * 16 + l16;
          af[mt] = *(const short8*)&sA[ml * 128 + (((ks * 4 + quad) ^ (ml & 7)) * 8)];
        }
#pragma unroll
        for (int nt = 0; nt < 4; nt++) {
          int nl = wn + nt * 16 + l16;
          bf[nt] = *(const short8*)&sB[nl * 128 + (((ks * 4 + quad) ^ (nl & 7)) * 8)];
        }
#pragma unroll
        for (int mt = 0; mt < 4; mt++)
#pragma unroll
          for (int nt = 0; nt < 4; nt++)
            acc[mt][nt] = __builtin_amdgcn_mfma_f32_16x16x32_bf16(
                af[mt], bf[nt], acc[mt][nt], 0, 0, 0);
      }
    }

    const int b = bm0 >> 11;
    const int tseq0 = (bm0 & 2047) + wm;

    if (bx < 10) {
      u16* Dst;
      if (bx < 8) {
        int hh = bx * 2 + (w & 1);
        int hkv = hh >> 2, g = hh & 3;
        Dst = Qb + ((long)((b * 4 + hkv) * 4 + g) * Tq) * 64;
      } else {
        int kk = (bx - 8) * 2 + (w & 1);
        Dst = Kb + ((long)(b * 4 + kk) * Tq) * 64;
      }
#pragma unroll
      for (int mt = 0; mt < 4; mt++) {
#pragma unroll
        for (int r = 0; r < 4; r++) {
          int t = tseq0 + mt * 16 + quad * 4 + r;
          float c0 = cosp[t * 32 + l16];
          float s0 = sinp[t * 32 + l16];
          float c1 = cosp[t * 32 + 16 + l16];
          float s1 = sinp[t * 32 + 16 + l16];
          float a0 = acc[mt][0][r], a1 = acc[mt][1][r];
          float a2 = acc[mt][2][r], a3 = acc[mt][3][r];
          float rp0 = a0 * c0 + a2 * s0;
          float rp1 = a1 * c1 + a3 * s1;
          float rp2 = a2 * c0 - a0 * s0;
          float rp3 = a3 * c1 - a1 * s1;
          float ss = rp0 * rp0 + rp1 * rp1 + rp2 * rp2 + rp3 * rp3;
          ss += __shfl_xor(ss, 1);
          ss += __shfl_xor(ss, 2);
          ss += __shfl_xor(ss, 4);
          ss += __shfl_xor(ss, 8);
          float sc = rsqrtf(ss * (1.f / 64.f) + 1.1920928955078125e-07f);
          u16* drow = Dst + (long)t * 64;
          drow[l16] = f2bf(rp0 * sc);
          drow[16 + l16] = f2bf(rp1 * sc);
          drow[32 + l16] = f2bf(rp2 * sc);
          drow[48 + l16] = f2bf(rp3 * sc);
        }
      }
    } else {
      int kk = (bx - 10) * 2 + (w & 1);
      u16* Dst = Vtb + ((long)(b * 4 + kk) * 64) * Tq;
#pragma unroll
      for (int mt = 0; mt < 4; mt++) {
        float vals[4][4];
#pragma unroll
        for (int r = 0; r < 4; r++) {
          int t = tseq0 + mt * 16 + quad * 4 + r;
          long bt = (long)b * Tq + t;
          float gv = gateb[bt * 4 + kk];
          const float* verow = ve + bt * 256 + kk * 64;
#pragma unroll
          for (int nt = 0; nt < 4; nt++)
            vals[nt][r] = acc[mt][nt][r] + gv * verow[nt * 16 + l16];
        }
        int t0m = tseq0 + mt * 16 + quad * 4;
#pragma unroll
        for (int nt = 0; nt < 4; nt++) {
          int d = nt * 16 + l16;
          union { short4 v; u16 u[4]; } pk;
#pragma unroll
          for (int r = 0; r < 4; r++) pk.u[r] = f2bf(vals[nt][r]);
          *(short4*)(Dst + (long)d * Tq + t0m) = pk.v;
        }
      }
    }
  }
  __threadfence();
  grid.sync();
  __threadfence();

  // ===================== phase 2: attention =====================
  {
    u16* KsB = smem;             // 2 x 128x64 bf16
    u16* VtB = smem + 16384;     // 2 x 64x128 bf16

    int bh = bid & 7;
    int qt32 = bid >> 3;
    int hkv = bh & 3;
    int b = bh >> 2;
    int q0 = qt32 * 32;
    int l31 = lane & 31;
    int hl = lane >> 5;

    short8 QB[4];
    {
      const u16* qb =
          Qb + ((long)((bh * 4 + w) * Tq + q0 + l31)) * 64 + hl * 8;
#pragma unroll
      for (int s = 0; s < 4; s++) QB[s] = *(const short8*)(qb + s * 16);
    }

    f32x16 O0, O1;
#pragma unroll
    for (int i = 0; i < 16; i++) { O0[i] = 0.f; O1[i] = 0.f; }
    float lsum = 0.f;

    int lo = q0 - (WSq - 1);
    int st = (lo < 0 ? 0 : lo) >> 7;
    int et = (q0 + 31) >> 7;

    const u16* Kbase = Kb + ((long)bh * Tq) * 64;
    const u16* Vbase = Vtb + ((long)bh * 64) * Tq;

    int rowoffK[4], rowoffV[4];
#pragma unroll
    for (int i = 0; i < 4; i++) {
      int s = i * 256 + tid;
      int kr = s >> 3, kgp = s & 7;
      rowoffK[i] = kr * 64 + (kgp ^ (kr & 7)) * 8;
      int d = s >> 4, vgp = s & 15;
      rowoffV[i] = d * Tq + (vgp ^ (d & 7)) * 8;
    }

    {
      int k0 = st << 7;
#pragma unroll
      for (int i = 0; i < 4; i++) {
        gl_lds16(Kbase + (long)k0 * 64 + rowoffK[i],
                 KsB + (i * 256 + w * 64) * 8);
        gl_lds16(Vbase + k0 + rowoffV[i], VtB + (i * 256 + w * 64) * 8);
      }
    }
    __syncthreads();

    int cur = 0;
    for (int kt = st; kt <= et; kt++) {
      int k0 = kt << 7;
      if (kt < et) {
        int k0n = k0 + 128;
        int nb = cur ^ 1;
#pragma unroll
        for (int i = 0; i < 4; i++) {
          gl_lds16(Kbase + (long)k0n * 64 + rowoffK[i],
                   KsB + nb * 8192 + (i * 256 + w * 64) * 8);
          gl_lds16(Vbase + k0n + rowoffV[i],
                   VtB + nb * 8192 + (i * 256 + w * 64) * 8);
        }
      }
      bool needC = (k0 + 127 > q0);
      bool needW = (k0 < q0 - 992);
      if (needC || needW) {
        attn_tile32<true>(k0, q0, l31, hl, KsB + cur * 8192, VtB + cur * 8192,
                          QB, O0, O1, lsum);
      } else {
        attn_tile32<false>(k0, q0, l31, hl, KsB + cur * 8192, VtB + cur * 8192,
                           QB, O0, O1, lsum);
      }
      __syncthreads();
      cur ^= 1;
    }

    lsum += __shfl_xor(lsum, 32);
    float invl = 1.f / lsum;

    int h = hkv * 4 + w;
    u16* yrow = xb + ((long)(b * Tq + q0 + l31)) * 1024 + h * 64;
#pragma unroll
    for (int g4 = 0; g4 < 4; g4++) {
      union { short4 v; u16 u[4]; } pk0, pk1;
#pragma unroll
      for (int i = 0; i < 4; i++) {
        pk0.u[i] = f2bf(O0[g4 * 4 + i] * invl);
        pk1.u[i] = f2bf(O1[g4 * 4 + i] * invl);
      }
      int dA = 8 * g4 + 4 * hl;
      *(short4*)(yrow + dA) = pk0.v;
      *(short4*)(yrow + 32 + dA) = pk1.v;
    }
  }
  __threadfence();
  grid.sync();
  __threadfence();

  // ===================== phase 3: proj GEMM =====================
  {
    const int bm0 = (bid >> 3) * 64, bn0 = (bid & 7) * 128;
    const int wm = (w >> 1) * 32, wn = (w & 1) * 64;
    const int K = 1024, N = 1024;
    u16* sA = smem;            // 64x128 bf16
    u16* sB = smem + 8192;     // 128x128 bf16

    f32x4 acc[2][4];
#pragma unroll
    for (int mt = 0; mt < 2; mt++)
#pragma unroll
      for (int nt = 0; nt < 4; nt++) acc[mt][nt] = (f32x4){0.f, 0.f, 0.f, 0.f};

    int goffA[4], goffB[8];
#pragma unroll
    for (int i = 0; i < 4; i++) {
      int s = i * 256 + tid;
      int m = s >> 4, gp = s & 15;
      goffA[i] = m * K + (gp ^ (m & 7)) * 8;
    }
#pragma unroll
    for (int i = 0; i < 8; i++) {
      int s = i * 256 + tid;
      int m = s >> 4, gp = s & 15;
      goffB[i] = m * K + (gp ^ (m & 7)) * 8;
    }
    const u16* Ab = xb + (long)bm0 * K;
    const u16* Bb = WprojT + (long)bn0 * K;

    for (int k0 = 0; k0 < K; k0 += 128) {
      __syncthreads();
#pragma unroll
      for (int i = 0; i < 4; i++)
        gl_lds16(Ab + goffA[i] + k0, &sA[(i * 256 + w * 64) * 8]);
#pragma unroll
      for (int i = 0; i < 8; i++)
        gl_lds16(Bb + goffB[i] + k0, &sB[(i * 256 + w * 64) * 8]);
      __syncthreads();

#pragma unroll
      for (int ks = 0; ks < 4; ks++) {
        short8 af[2], bf[4];
#pragma unroll
        for (int mt = 0; mt < 2; mt++) {
          int ml = wm + mt * 16 + l16;
          af[mt] = *(const short8*)&sA[ml * 128 + (((ks * 4 + quad) ^ (ml & 7)) * 8)];
        }
#pragma unroll
        for (int nt = 0; nt < 4; nt++) {
          int nl = wn + nt * 16 + l16;
          bf[nt] = *(const short8*)&sB[nl * 128 + (((ks * 4 + quad) ^ (nl & 7)) * 8)];
        }
#pragma unroll
        for (int mt = 0; mt < 2; mt++)
#pragma unroll
          for (int nt = 0; nt < 4; nt++)
            acc[mt][nt] = __builtin_amdgcn_mfma_f32_16x16x32_bf16(
                af[mt], bf[nt], acc[mt][nt], 0, 0, 0);
      }
    }

#pragma unroll
    for (int mt = 0; mt < 2; mt++)
#pragma unroll
      for (int nt = 0; nt < 4; nt++) {
        int row0 = bm0 + wm + mt * 16 + quad * 4;
        int col = bn0 + wn + nt * 16 + l16;
#pragma unroll
        for (int r = 0; r < 4; r++)
          out[(long)(row0 + r) * N + col] = acc[mt][nt][r];
      }
  }
}

// ===========================================================================
// Fallback path: the round-4 verified 4-kernel pipeline (BK=128 GEMMs).
// ===========================================================================
__global__ __launch_bounds__(256) void qkv_gemm_fused(
    const u16* __restrict__ A, const u16* __restrict__ Bt,
    const float* __restrict__ ve, const float* __restrict__ cosp,
    const float* __restrict__ sinp, const float* __restrict__ gatebuf,
    u16* __restrict__ Qb, u16* __restrict__ Kb, u16* __restrict__ Vtb) {
  __shared__ __attribute__((aligned(16))) u16 As[64 * 128];    // 16 KB
  __shared__ __attribute__((aligned(16))) u16 Bs[128 * 128];   // 32 KB

  const int bx = blockIdx.x;
  const int bm0 = blockIdx.y * 64, bn0 = bx * 128;
  const int tid = threadIdx.x;
  const int w = tid >> 6, lane = tid & 63;
  const int wm = (w >> 1) * 32, wn = (w & 1) * 64;
  const int quad = lane >> 4, l16 = lane & 15;
  const int K = 1024;

  f32x4 acc[2][4];
#pragma unroll
  for (int mt = 0; mt < 2; mt++)
#pragma unroll
    for (int nt = 0; nt < 4; nt++) acc[mt][nt] = (f32x4){0.f, 0.f, 0.f, 0.f};

  int goffA[4], goffB[8];
#pragma unroll
  for (int i = 0; i < 4; i++) {
    int s = i * 256 + tid;
    int m = s >> 4, gp = s & 15;
    goffA[i] = m * K + (gp ^ (m & 7)) * 8;
  }
#pragma unroll
  for (int i = 0; i < 8; i++) {
    int s = i * 256 + tid;
    int m = s >> 4, gp = s & 15;
    goffB[i] = m * K + (gp ^ (m & 7)) * 8;
  }
  const u16* Ab = A + (long)bm0 * K;
  const u16* Bb = Bt + (long)bn0 * K;

  for (int k0 = 0; k0 < K; k0 += 128) {
    __syncthreads();
#pragma unroll
    for (int i = 0; i < 4; i++)
      gl_lds16(Ab + goffA[i] + k0, &As[(i * 256 + w * 64) * 8]);
#pragma unroll
    for (int i = 0; i < 8; i++)
      gl_lds16(Bb + goffB[i] + k0, &Bs[(i * 256 + w * 64) * 8]);
    __syncthreads();

#pragma unroll
    for (int ks = 0; ks < 4; ks++) {
      short8 af[2], bf[4];
#pragma unroll
      for (int mt = 0; mt < 2; mt++) {
        int ml = wm + mt * 16 + l16;
        af[mt] = *(const short8*)&As[ml * 128 + (((ks * 4 + quad) ^ (ml & 7)) * 8)];
      }
#pragma unroll
      for (int nt = 0; nt < 4; nt++) {
        int nl = wn + nt * 16 + l16;
        bf[nt] = *(const short8*)&Bs[nl * 128 + (((ks * 4 + quad) ^ (nl & 7)) * 8)];
      }
#pragma unroll
      for (int mt = 0; mt < 2; mt++)
#pragma unroll
        for (int nt = 0; nt < 4; nt++)
          acc[mt][nt] = __builtin_amdgcn_mfma_f32_16x16x32_bf16(
              af[mt], bf[nt], acc[mt][nt], 0, 0, 0);
    }
  }

  const int b = bm0 >> 11;
  const int tseq0 = (bm0 & 2047) + wm;

  if (bx < 10) {
    u16* Dst;
    if (bx < 8) {
      int hh = bx * 2 + (w & 1);
      int hkv = hh >> 2, g = hh & 3;
      Dst = Qb + ((long)((b * 4 + hkv) * 4 + g) * Tq) * 64;
    } else {
      int kk = (bx - 8) * 2 + (w & 1);
      Dst = Kb + ((long)(b * 4 + kk) * Tq) * 64;
    }
#pragma unroll
    for (int mt = 0; mt < 2; mt++) {
#pragma unroll
      for (int r = 0; r < 4; r++) {
        int t = tseq0 + mt * 16 + quad * 4 + r;
        float c0 = cosp[t * 32 + l16];
        float s0 = sinp[t * 32 + l16];
        float c1 = cosp[t * 32 + 16 + l16];
        float s1 = sinp[t * 32 + 16 + l16];
        float a0 = acc[mt][0][r], a1 = acc[mt][1][r];
        float a2 = acc[mt][2][r], a3 = acc[mt][3][r];
        float rp0 = a0 * c0 + a2 * s0;
        float rp1 = a1 * c1 + a3 * s1;
        float rp2 = a2 * c0 - a0 * s0;
        float rp3 = a3 * c1 - a1 * s1;
        float ss = rp0 * rp0 + rp1 * rp1 + rp2 * rp2 + rp3 * rp3;
        ss += __shfl_xor(ss, 1);
        ss += __shfl_xor(ss, 2);
        ss += __shfl_xor(ss, 4);
        ss += __shfl_xor(ss, 8);
        float sc = rsqrtf(ss * (1.f / 64.f) + 1.1920928955078125e-07f);
        u16* drow = Dst + (long)t * 64;
        drow[l16] = f2bf(rp0 * sc);
        drow[16 + l16] = f2bf(rp1 * sc);
        drow[32 + l16] = f2bf(rp2 * sc);
        drow[48 + l16] = f2bf(rp3 * sc);
      }
    }
  } else {
    int kk = (bx - 10) * 2 + (w & 1);
    u16* Dst = Vtb + ((long)(b * 4 + kk) * 64) * Tq;
#pragma unroll
    for (int mt = 0; mt < 2; mt++) {
      float vals[4][4];
#pragma unroll
      for (int r = 0; r < 4; r++) {
        int t = tseq0 + mt * 16 + quad * 4 + r;
        long bt = (long)b * Tq + t;
        float gv = gatebuf[bt * 4 + kk];
        const float* verow = ve + bt * 256 + kk * 64;
#pragma unroll
        for (int nt = 0; nt < 4; nt++)
          vals[nt][r] = acc[mt][nt][r] + gv * verow[nt * 16 + l16];
      }
      int t0m = tseq0 + mt * 16 + quad * 4;
#pragma unroll
      for (int nt = 0; nt < 4; nt++) {
        int d = nt * 16 + l16;
        union { short4 v; u16 u[4]; } p;
#pragma unroll
        for (int r = 0; r < 4; r++) p.u[r] = f2bf(vals[nt][r]);
        *(short4*)(Dst + (long)d * Tq + t0m) = p.v;
      }
    }
  }
}

__global__ __launch_bounds__(256) void gemm_proj(
    const u16* __restrict__ A, const u16* __restrict__ Bt,
    float* __restrict__ C, int M, int N, int K) {
  __shared__ __attribute__((aligned(16))) u16 As[64 * 128];
  __shared__ __attribute__((aligned(16))) u16 Bs[128 * 128];

  const int bm0 = blockIdx.y * 64, bn0 = blockIdx.x * 128;
  const int tid = threadIdx.x;
  const int w = tid >> 6, lane = tid & 63;
  const int wm = (w >> 1) * 32, wn = (w & 1) * 64;
  const int quad = lane >> 4, l16 = lane & 15;

  f32x4 acc[2][4];
#pragma unroll
  for (int mt = 0; mt < 2; mt++)
#pragma unroll
    for (int nt = 0; nt < 4; nt++) acc[mt][nt] = (f32x4){0.f, 0.f, 0.f, 0.f};

  int goffA[4], goffB[8];
#pragma unroll
  for (int i = 0; i < 4; i++) {
    int s = i * 256 + tid;
    int m = s >> 4, gp = s & 15;
    goffA[i] = m * K + (gp ^ (m & 7)) * 8;
  }
#pragma unroll
  for (int i = 0; i < 8; i++) {
    int s = i * 256 + tid;
    int m = s >> 4, gp = s & 15;
    goffB[i] = m * K + (gp ^ (m & 7)) * 8;
  }
  const u16* Ab = A + (long)bm0 * K;
  const u16* Bb = Bt + (long)bn0 * K;

  for (int k0 = 0; k0 < K; k0 += 128) {
    __syncthreads();
#pragma unroll
    for (int i = 0; i < 4; i++)
      gl_lds16(Ab + goffA[i] + k0, &As[(i * 256 + w * 64) * 8]);
#pragma unroll
    for (int i = 0; i < 8; i++)
      gl_lds16(Bb + goffB[i] + k0, &Bs[(i * 256 + w * 64) * 8]);
    __syncthreads();

#pragma unroll
    for (int ks = 0; ks < 4; ks++) {
      short8 af[2], bf[4];
#pragma unroll
      for (int mt = 0; mt < 2; mt++) {
        int ml = wm + mt * 16 + l16;
        af[mt] = *(const short8*)&As[ml * 128 + (((ks * 4 + quad) ^ (ml & 7)) * 8)];
      }
#pragma unroll
      for (int nt = 0; nt < 4; nt++) {
        int nl = wn + nt * 16 + l16;
        bf[nt] = *(const short8*)&Bs[nl * 128 + (((ks * 4 + quad) ^ (nl & 7)) * 8)];
      }
#pragma unroll
      for (int mt = 0; mt < 2; mt++)
#pragma unroll
        for (int nt = 0; nt < 4; nt++)
          acc[mt][nt] = __builtin_amdgcn_mfma_f32_16x16x32_bf16(
              af[mt], bf[nt], acc[mt][nt], 0, 0, 0);
    }
  }

#pragma unroll
  for (int mt = 0; mt < 2; mt++)
#pragma unroll
    for (int nt = 0; nt < 4; nt++) {
      int row0 = bm0 + wm + mt * 16 + quad * 4;
      int col = bn0 + wn + nt * 16 + l16;
#pragma unroll
      for (int r = 0; r < 4; r++)
        C[(long)(row0 + r) * N + col] = acc[mt][nt][r];
    }
}

__global__ __launch_bounds__(256) void prep(
    const float* __restrict__ x, u16* __restrict__ xb,
    const float* __restrict__ Wq, const float* __restrict__ Wk,
    const float* __restrict__ Wv, const float* __restrict__ Wproj,
    const float* __restrict__ Wg, u16* __restrict__ Dqkv,
    u16* __restrict__ Dproj, float* __restrict__ gatebuf) {
  __shared__ float tile[64][65];
  int bx = blockIdx.x;
  int tid = threadIdx.x;
  if (bx < 2048) {
    int i = (bx * 256 + tid) * 8;
    float4 a = *(const float4*)(x + i);
    float4 b = *(const float4*)(x + i + 4);
    union { short8 v; u16 u[8]; } o;
    o.u[0] = f2bf(a.x); o.u[1] = f2bf(a.y); o.u[2] = f2bf(a.z); o.u[3] = f2bf(a.w);
    o.u[4] = f2bf(b.x); o.u[5] = f2bf(b.y); o.u[6] = f2bf(b.z); o.u[7] = f2bf(b.w);
    *(short8*)(xb + i) = o.v;
    return;
  }
  if (bx >= 2688) {
    int p = (bx - 2688) * 256 + tid;
    int bt = p >> 2, kk = p & 3;
    const float* xr = x + (long)bt * Cq;
    float dot = 0.f;
#pragma unroll
    for (int i = 0; i < GATE_CHq; i++) dot += xr[i] * Wg[i * HKVq + kk];
    gatebuf[p] = 2.f / (1.f + expf(-dot));
    return;
  }
  int wb = bx - 2048;
  int obx = wb >> 4;
  int k0 = (wb & 15) * 64;
  const float* S;
  u16* Dst;
  int N, nb;
  if (obx < 16)      { S = Wq;    N = 1024; nb = obx;      Dst = Dqkv; }
  else if (obx < 20) { S = Wk;    N = 256;  nb = obx - 16; Dst = Dqkv + 1024 * 1024; }
  else if (obx < 24) { S = Wv;    N = 256;  nb = obx - 20; Dst = Dqkv + 1280 * 1024; }
  else               { S = Wproj; N = 1024; nb = obx - 24; Dst = Dproj; }
  int n0 = nb * 64;
#pragma unroll
  for (int i = 0; i < 16; i++) {
    int idx = i * 256 + tid;
    int kl = idx >> 6, nl = idx & 63;
    tile[kl][nl] = S[(long)(k0 + kl) * N + n0 + nl];
  }
  __syncthreads();
#pragma unroll
  for (int i = 0; i < 16; i++) {
    int idx = i * 256 + tid;
    int nl = idx >> 6, kl = idx & 63;
    Dst[(long)(n0 + nl) * 1024 + k0 + kl] = f2bf(tile[kl][nl]);
  }
}

__global__ __launch_bounds__(256, 2) void attn_mfma(
    const u16* __restrict__ Qb, const u16* __restrict__ Kb,
    const u16* __restrict__ Vtb, u16* __restrict__ Yb) {
  __shared__ __attribute__((aligned(16))) u16 Ks[2][128 * 64];
  __shared__ __attribute__((aligned(16))) u16 Vts[2][64 * 128];

  int bid = blockIdx.x;
  int bh = bid & 7;
  int qt32 = bid >> 3;
  int hkv = bh & 3;
  int b = bh >> 2;
  int q0 = qt32 * 32;
  int tid = threadIdx.x;
  int g = tid >> 6;
  int lane = tid & 63;
  int l31 = lane & 31;
  int hl = lane >> 5;

  short8 QB[4];
  {
    const u16* qb =
        Qb + ((long)((bh * 4 + g) * Tq + q0 + l31)) * 64 + hl * 8;
#pragma unroll
    for (int s = 0; s < 4; s++) QB[s] = *(const short8*)(qb + s * 16);
  }

  f32x16 O0, O1;
#pragma unroll
  for (int i = 0; i < 16; i++) { O0[i] = 0.f; O1[i] = 0.f; }
  float lsum = 0.f;

  int lo = q0 - (WSq - 1);
  int st = (lo < 0 ? 0 : lo) >> 7;
  int et = (q0 + 31) >> 7;

  const u16* Kbase = Kb + ((long)bh * Tq) * 64;
  const u16* Vbase = Vtb + ((long)bh * 64) * Tq;

  int rowoffK[4], rowoffV[4];
#pragma unroll
  for (int i = 0; i < 4; i++) {
    int s = i * 256 + tid;
    int kr = s >> 3, kgp = s & 7;
    rowoffK[i] = kr * 64 + (kgp ^ (kr & 7)) * 8;
    int d = s >> 4, vgp = s & 15;
    rowoffV[i] = d * Tq + (vgp ^ (d & 7)) * 8;
  }

  {
    int k0 = st << 7;
#pragma unroll
    for (int i = 0; i < 4; i++) {
      gl_lds16(Kbase + (long)k0 * 64 + rowoffK[i], &Ks[0][(i * 256 + g * 64) * 8]);
      gl_lds16(Vbase + k0 + rowoffV[i], &Vts[0][(i * 256 + g * 64) * 8]);
    }
  }
  __syncthreads();

  int cur = 0;
  for (int kt = st; kt <= et; kt++) {
    int k0 = kt << 7;
    if (kt < et) {
      int k0n = k0 + 128;
#pragma unroll
      for (int i = 0; i < 4; i++) {
        gl_lds16(Kbase + (long)k0n * 64 + rowoffK[i],
                 &Ks[cur ^ 1][(i * 256 + g * 64) * 8]);
        gl_lds16(Vbase + k0n + rowoffV[i],
                 &Vts[cur ^ 1][(i * 256 + g * 64) * 8]);
      }
    }
    bool needC = (k0 + 127 > q0);
    bool needW = (k0 < q0 - 992);
    if (needC || needW) {
      attn_tile32<true>(k0, q0, l31, hl, Ks[cur], Vts[cur], QB, O0, O1, lsum);
    } else {
      attn_tile32<false>(k0, q0, l31, hl, Ks[cur], Vts[cur], QB, O0, O1, lsum);
    }
    __syncthreads();
    cur ^= 1;
  }

  lsum += __shfl_xor(lsum, 32);
  float invl = 1.f / lsum;

  int h = hkv * 4 + g;
  u16* yrow = Yb + ((long)(b * Tq + q0 + l31)) * 1024 + h * 64;
#pragma unroll
  for (int g4 = 0; g4 < 4; g4++) {
    union { short4 v; u16 u[4]; } pk0, pk1;
#pragma unroll
    for (int i = 0; i < 4; i++) {
      pk0.u[i] = f2bf(O0[g4 * 4 + i] * invl);
      pk1.u[i] = f2bf(O1[g4 * 4 + i] * invl);
    }
    int dA = 8 * g4 + 4 * hl;
    *(short4*)(yrow + dA) = pk0.v;
    *(short4*)(yrow + 32 + dA) = pk1.v;
  }
}

// ---------------------------------------------------------------------------
extern "C" void kernel_launch(void* const* d_in, const int* in_sizes, int n_in,
                              void* d_out, int out_size, void* d_ws,
                              size_t ws_size, hipStream_t stream) {
  const float* x     = (const float*)d_in[0];
  const float* ve    = (const float*)d_in[1];
  const float* cosp  = (const float*)d_in[2];
  const float* sinp  = (const float*)d_in[3];
  const float* Wq    = (const float*)d_in[4];
  const float* Wk    = (const float*)d_in[5];
  const float* Wv    = (const float*)d_in[6];
  const float* Wproj = (const float*)d_in[7];
  const float* Wg    = (const float*)d_in[8];

  char* base = (char*)d_ws;
  u16* xb      = (u16*)(base);
  u16* WqkvT   = (u16*)(base + 8388608);
  u16* WprojT  = (u16*)(base + 11534336);
  u16* Qb      = (u16*)(base + 13631488);
  u16* Kb      = (u16*)(base + 22020096);
  u16* Vtb     = (u16*)(base + 24117248);
  float* gateb = (float*)(base + 26214400);
  float* out   = (float*)d_out;

  void* args[] = {(void*)&x,     (void*)&ve,    (void*)&cosp, (void*)&sinp,
                  (void*)&Wq,    (void*)&Wk,    (void*)&Wv,   (void*)&Wproj,
                  (void*)&Wg,    (void*)&xb,    (void*)&WqkvT,
                  (void*)&WprojT,(void*)&Qb,    (void*)&Kb,   (void*)&Vtb,
                  (void*)&gateb, (void*)&out};
  hipError_t err = hipLaunchCooperativeKernel((const void*)mega, dim3(512),
                                              dim3(256), args, 0, stream);
  if (err != hipSuccess) {
    // Cooperative launch rejected (e.g. under graph capture): run the
    // verified 4-kernel pipeline instead.
    prep<<<2752, 256, 0, stream>>>(x, xb, Wq, Wk, Wv, Wproj, Wg, WqkvT, WprojT,
                                   gateb);
    qkv_gemm_fused<<<dim3(12, 64), 256, 0, stream>>>(xb, WqkvT, ve, cosp, sinp,
                                                     gateb, Qb, Kb, Vtb);
    attn_mfma<<<512, 256, 0, stream>>>(Qb, Kb, Vtb, xb);
    gemm_proj<<<dim3(8, 64), 256, 0, stream>>>(xb, WprojT, out, 4096, 1024,
                                               1024);
  }
}

// Round 7
// 172.855 us; speedup vs baseline: 3.5448x; 3.5448x over previous
//
#include <hip/hip_runtime.h>
#include <hip/hip_bf16.h>

// Problem constants
#define Bq 2
#define Tq 2048
#define Cq 1024
#define Hq 16
#define HKVq 4
#define HDq 64
#define Gq 4
#define WSq 1024
#define GATE_CHq 32

typedef __attribute__((ext_vector_type(8))) short short8;   // 8 bf16 (4 VGPRs)
typedef __attribute__((ext_vector_type(4))) float f32x4;    // MFMA C/D frag
typedef __attribute__((ext_vector_type(16))) float f32x16;  // 32x32 MFMA C/D
typedef __attribute__((ext_vector_type(2))) unsigned int u32x2;
typedef unsigned int u32;
typedef unsigned short u16;

#if __has_builtin(__builtin_amdgcn_exp2f)
#define EXP2(x) __builtin_amdgcn_exp2f(x)
#else
#define EXP2(x) exp2f(x)
#endif

__device__ __forceinline__ u16 f2bf(float f) {
  u32 u = __float_as_uint(f);
  u32 r = (u + 0x7FFFu + ((u >> 16) & 1u)) >> 16;  // RNE
  return (u16)r;
}

__device__ __forceinline__ void gl_lds16(const u16* g, u16* l) {
  __builtin_amdgcn_global_load_lds(
      (const u32 __attribute__((address_space(1)))*)g,
      (u32 __attribute__((address_space(3)))*)l, 16, 0, 0);
}

// ---------------------------------------------------------------------------
// Fused QKV GEMM + RoPE/RMSNorm/gate epilogue.
// m97-proven geometry: 128x128 C-tile, BK=64, 4x4 acc/wave, 32 KB LDS
// (3 blocks/CU). A[4096][1024] @ WqkvT[1536][1024]^T.
// bx 0..7: Q (2 heads/block); 8..9: K; 10..11: V.  grid (12, 32).
// Epilogue verified in round-6 mega (phase 1).
// ---------------------------------------------------------------------------
__global__ __launch_bounds__(256) void qkv_gemm_fused(
    const u16* __restrict__ A, const u16* __restrict__ Bt,
    const float* __restrict__ ve, const float* __restrict__ cosp,
    const float* __restrict__ sinp, const float* __restrict__ gatebuf,
    u16* __restrict__ Qb, u16* __restrict__ Kb, u16* __restrict__ Vtb) {
  __shared__ __attribute__((aligned(16))) u16 As[128 * 64];   // 16 KB
  __shared__ __attribute__((aligned(16))) u16 Bs[128 * 64];   // 16 KB

  const int bx = blockIdx.x;
  const int bm0 = blockIdx.y * 128, bn0 = bx * 128;
  const int tid = threadIdx.x;
  const int w = tid >> 6, lane = tid & 63;
  const int wm = (w >> 1) * 64, wn = (w & 1) * 64;
  const int quad = lane >> 4, l16 = lane & 15;
  const int K = 1024;

  f32x4 acc[4][4];
#pragma unroll
  for (int mt = 0; mt < 4; mt++)
#pragma unroll
    for (int nt = 0; nt < 4; nt++) acc[mt][nt] = (f32x4){0.f, 0.f, 0.f, 0.f};

  int goff[4];
#pragma unroll
  for (int i = 0; i < 4; i++) {
    int s = i * 256 + tid;
    int m = s >> 3, gp = s & 7;
    goff[i] = m * K + (gp ^ (m & 7)) * 8;
  }
  const u16* Ab = A + (long)bm0 * K;
  const u16* Bb = Bt + (long)bn0 * K;

  for (int k0 = 0; k0 < K; k0 += 64) {
    __syncthreads();
#pragma unroll
    for (int i = 0; i < 4; i++) {
      gl_lds16(Ab + goff[i] + k0, &As[(i * 256 + w * 64) * 8]);
      gl_lds16(Bb + goff[i] + k0, &Bs[(i * 256 + w * 64) * 8]);
    }
    __syncthreads();

#pragma unroll
    for (int ks = 0; ks < 2; ks++) {
      short8 af[4], bf[4];
#pragma unroll
      for (int mt = 0; mt < 4; mt++) {
        int ml = wm + mt * 16 + l16;
        af[mt] = *(const short8*)&As[ml * 64 + (((ks * 4 + quad) ^ (ml & 7)) * 8)];
      }
#pragma unroll
      for (int nt = 0; nt < 4; nt++) {
        int nl = wn + nt * 16 + l16;
        bf[nt] = *(const short8*)&Bs[nl * 64 + (((ks * 4 + quad) ^ (nl & 7)) * 8)];
      }
#pragma unroll
      for (int mt = 0; mt < 4; mt++)
#pragma unroll
        for (int nt = 0; nt < 4; nt++)
          acc[mt][nt] = __builtin_amdgcn_mfma_f32_16x16x32_bf16(
              af[mt], bf[nt], acc[mt][nt], 0, 0, 0);
    }
  }

  // ---- fused epilogue (round-6-mega-verified) ----
  const int b = bm0 >> 11;
  const int tseq0 = (bm0 & 2047) + wm;

  if (bx < 10) {
    u16* Dst;
    if (bx < 8) {
      int hh = bx * 2 + (w & 1);
      int hkv = hh >> 2, g = hh & 3;
      Dst = Qb + ((long)((b * 4 + hkv) * 4 + g) * Tq) * 64;
    } else {
      int kk = (bx - 8) * 2 + (w & 1);
      Dst = Kb + ((long)(b * 4 + kk) * Tq) * 64;
    }
#pragma unroll
    for (int mt = 0; mt < 4; mt++) {
#pragma unroll
      for (int r = 0; r < 4; r++) {
        int t = tseq0 + mt * 16 + quad * 4 + r;
        float c0 = cosp[t * 32 + l16];
        float s0 = sinp[t * 32 + l16];
        float c1 = cosp[t * 32 + 16 + l16];
        float s1 = sinp[t * 32 + 16 + l16];
        float a0 = acc[mt][0][r], a1 = acc[mt][1][r];
        float a2 = acc[mt][2][r], a3 = acc[mt][3][r];
        float rp0 = a0 * c0 + a2 * s0;
        float rp1 = a1 * c1 + a3 * s1;
        float rp2 = a2 * c0 - a0 * s0;
        float rp3 = a3 * c1 - a1 * s1;
        float ss = rp0 * rp0 + rp1 * rp1 + rp2 * rp2 + rp3 * rp3;
        ss += __shfl_xor(ss, 1);
        ss += __shfl_xor(ss, 2);
        ss += __shfl_xor(ss, 4);
        ss += __shfl_xor(ss, 8);
        float sc = rsqrtf(ss * (1.f / 64.f) + 1.1920928955078125e-07f);
        u16* drow = Dst + (long)t * 64;
        drow[l16] = f2bf(rp0 * sc);
        drow[16 + l16] = f2bf(rp1 * sc);
        drow[32 + l16] = f2bf(rp2 * sc);
        drow[48 + l16] = f2bf(rp3 * sc);
      }
    }
  } else {
    int kk = (bx - 10) * 2 + (w & 1);
    u16* Dst = Vtb + ((long)(b * 4 + kk) * 64) * Tq;
#pragma unroll
    for (int mt = 0; mt < 4; mt++) {
      float vals[4][4];
#pragma unroll
      for (int r = 0; r < 4; r++) {
        int t = tseq0 + mt * 16 + quad * 4 + r;
        long bt = (long)b * Tq + t;
        float gv = gatebuf[bt * 4 + kk];
        const float* verow = ve + bt * 256 + kk * 64;
#pragma unroll
        for (int nt = 0; nt < 4; nt++)
          vals[nt][r] = acc[mt][nt][r] + gv * verow[nt * 16 + l16];
      }
      int t0m = tseq0 + mt * 16 + quad * 4;
#pragma unroll
      for (int nt = 0; nt < 4; nt++) {
        int d = nt * 16 + l16;
        union { short4 v; u16 u[4]; } pk;
#pragma unroll
        for (int r = 0; r < 4; r++) pk.u[r] = f2bf(vals[nt][r]);
        *(short4*)(Dst + (long)d * Tq + t0m) = pk.v;
      }
    }
  }
}

// ---------------------------------------------------------------------------
// proj GEMM (f32 out), 128x128 tile, BK=64, 4x4 acc/wave.  grid (8, 32).
// ---------------------------------------------------------------------------
__global__ __launch_bounds__(256) void gemm_proj(
    const u16* __restrict__ A, const u16* __restrict__ Bt,
    float* __restrict__ C, int M, int N, int K) {
  __shared__ __attribute__((aligned(16))) u16 As[128 * 64];
  __shared__ __attribute__((aligned(16))) u16 Bs[128 * 64];

  const int bm0 = blockIdx.y * 128, bn0 = blockIdx.x * 128;
  const int tid = threadIdx.x;
  const int w = tid >> 6, lane = tid & 63;
  const int wm = (w >> 1) * 64, wn = (w & 1) * 64;
  const int quad = lane >> 4, l16 = lane & 15;

  f32x4 acc[4][4];
#pragma unroll
  for (int mt = 0; mt < 4; mt++)
#pragma unroll
    for (int nt = 0; nt < 4; nt++) acc[mt][nt] = (f32x4){0.f, 0.f, 0.f, 0.f};

  int goff[4];
#pragma unroll
  for (int i = 0; i < 4; i++) {
    int s = i * 256 + tid;
    int m = s >> 3, gp = s & 7;
    goff[i] = m * K + (gp ^ (m & 7)) * 8;
  }
  const u16* Ab = A + (long)bm0 * K;
  const u16* Bb = Bt + (long)bn0 * K;

  for (int k0 = 0; k0 < K; k0 += 64) {
    __syncthreads();
#pragma unroll
    for (int i = 0; i < 4; i++) {
      gl_lds16(Ab + goff[i] + k0, &As[(i * 256 + w * 64) * 8]);
      gl_lds16(Bb + goff[i] + k0, &Bs[(i * 256 + w * 64) * 8]);
    }
    __syncthreads();

#pragma unroll
    for (int ks = 0; ks < 2; ks++) {
      short8 af[4], bf[4];
#pragma unroll
      for (int mt = 0; mt < 4; mt++) {
        int ml = wm + mt * 16 + l16;
        af[mt] = *(const short8*)&As[ml * 64 + (((ks * 4 + quad) ^ (ml & 7)) * 8)];
      }
#pragma unroll
      for (int nt = 0; nt < 4; nt++) {
        int nl = wn + nt * 16 + l16;
        bf[nt] = *(const short8*)&Bs[nl * 64 + (((ks * 4 + quad) ^ (nl & 7)) * 8)];
      }
#pragma unroll
      for (int mt = 0; mt < 4; mt++)
#pragma unroll
        for (int nt = 0; nt < 4; nt++)
          acc[mt][nt] = __builtin_amdgcn_mfma_f32_16x16x32_bf16(
              af[mt], bf[nt], acc[mt][nt], 0, 0, 0);
    }
  }

#pragma unroll
  for (int mt = 0; mt < 4; mt++)
#pragma unroll
    for (int nt = 0; nt < 4; nt++) {
      int row0 = bm0 + wm + mt * 16 + quad * 4;
      int col = bn0 + wn + nt * 16 + l16;
#pragma unroll
      for (int r = 0; r < 4; r++)
        C[(long)(row0 + r) * N + col] = acc[mt][nt][r];
    }
}

// ---------------------------------------------------------------------------
// prep: x->bf16 (0..2047) + weight transposes (2048..2687) + gate (2688..2751)
// ---------------------------------------------------------------------------
__global__ __launch_bounds__(256) void prep(
    const float* __restrict__ x, u16* __restrict__ xb,
    const float* __restrict__ Wq, const float* __restrict__ Wk,
    const float* __restrict__ Wv, const float* __restrict__ Wproj,
    const float* __restrict__ Wg, u16* __restrict__ Dqkv,
    u16* __restrict__ Dproj, float* __restrict__ gatebuf) {
  __shared__ float tile[64][65];
  int bx = blockIdx.x;
  int tid = threadIdx.x;
  if (bx < 2048) {
    int i = (bx * 256 + tid) * 8;
    float4 a = *(const float4*)(x + i);
    float4 b = *(const float4*)(x + i + 4);
    union { short8 v; u16 u[8]; } o;
    o.u[0] = f2bf(a.x); o.u[1] = f2bf(a.y); o.u[2] = f2bf(a.z); o.u[3] = f2bf(a.w);
    o.u[4] = f2bf(b.x); o.u[5] = f2bf(b.y); o.u[6] = f2bf(b.z); o.u[7] = f2bf(b.w);
    *(short8*)(xb + i) = o.v;
    return;
  }
  if (bx >= 2688) {
    int p = (bx - 2688) * 256 + tid;   // 0..16383
    int bt = p >> 2, kk = p & 3;
    const float* xr = x + (long)bt * Cq;
    float dot = 0.f;
#pragma unroll
    for (int i = 0; i < GATE_CHq; i++) dot += xr[i] * Wg[i * HKVq + kk];
    gatebuf[p] = 2.f / (1.f + expf(-dot));
    return;
  }
  int wb = bx - 2048;             // 0..639
  int obx = wb >> 4;              // 0..39
  int k0 = (wb & 15) * 64;
  const float* S;
  u16* Dst;
  int N, nb;
  if (obx < 16)      { S = Wq;    N = 1024; nb = obx;      Dst = Dqkv; }
  else if (obx < 20) { S = Wk;    N = 256;  nb = obx - 16; Dst = Dqkv + 1024 * 1024; }
  else if (obx < 24) { S = Wv;    N = 256;  nb = obx - 20; Dst = Dqkv + 1280 * 1024; }
  else               { S = Wproj; N = 1024; nb = obx - 24; Dst = Dproj; }
  int n0 = nb * 64;
#pragma unroll
  for (int i = 0; i < 16; i++) {
    int idx = i * 256 + tid;
    int kl = idx >> 6, nl = idx & 63;
    tile[kl][nl] = S[(long)(k0 + kl) * N + n0 + nl];
  }
  __syncthreads();
#pragma unroll
  for (int i = 0; i < 16; i++) {
    int idx = i * 256 + tid;
    int nl = idx >> 6, kl = idx & 63;
    Dst[(long)(n0 + nl) * 1024 + k0 + kl] = f2bf(tile[kl][nl]);
  }
}

// ---------------------------------------------------------------------------
// MFMA flash attention v5c: 32x32x16 MFMA, swapped operands both ways.
// S^T = K·Q^T; P packed+permlane32_swap in-register; O^T = V^T·P^T.
// K/V double-buffered; prefetch before compute; one barrier per tile.
// ---------------------------------------------------------------------------
#define CEXP 0.18033688011112042f   // 0.125 * log2(e)
#define CEXP8 1.4426950408889634f   // 8 * 0.125 * log2(e)

template <bool MASK>
__device__ __forceinline__ void attn_tile32(
    int k0, int q0, int l31, int hl, const u16* __restrict__ Ks,
    const u16* __restrict__ Vts, const short8 (&QB)[4], f32x16& O0, f32x16& O1,
    float& lsum) {
  const int qpos = q0 + l31;
#pragma unroll
  for (int c = 0; c < 4; c++) {
    const int key = c * 32 + l31;
    f32x16 S;
#pragma unroll
    for (int i = 0; i < 16; i++) S[i] = 0.f;
    __builtin_amdgcn_s_setprio(1);
#pragma unroll
    for (int s = 0; s < 4; s++) {
      short8 kf = *(const short8*)&Ks[key * 64 + (((s * 2 + hl) ^ (key & 7)) * 8)];
      S = __builtin_amdgcn_mfma_f32_32x32x16_bf16(kf, QB[s], S, 0, 0, 0);
    }
    __builtin_amdgcn_s_setprio(0);
    const int kb = k0 + c * 32 + 4 * hl;
    float p[16];
    float la0 = 0.f, la1 = 0.f;
#pragma unroll
    for (int r = 0; r < 16; r++) {
      float sv = S[r];
      if (MASK) {
        int kpos = kb + (r & 3) + 8 * (r >> 2);
        u32 diff = (u32)(qpos - kpos);
        sv = (diff < (u32)WSq) ? sv : -1e30f;
      }
      float pv = EXP2(__builtin_fmaf(sv, CEXP, -CEXP8));
      if (r & 1) la1 += pv; else la0 += pv;
      p[r] = pv;
    }
    lsum += la0 + la1;
    u32 w8[8];
#pragma unroll
    for (int i = 0; i < 8; i++) {
      u32 lo = __float_as_uint(p[2 * i]) + 0x8000u;
      u32 hi = __float_as_uint(p[2 * i + 1]) + 0x8000u;
      w8[i] = __builtin_amdgcn_perm(hi, lo, 0x07060302u);
    }
    u32x2 r02 = __builtin_amdgcn_permlane32_swap(w8[0], w8[2], false, false);
    u32x2 r13 = __builtin_amdgcn_permlane32_swap(w8[1], w8[3], false, false);
    u32x2 r46 = __builtin_amdgcn_permlane32_swap(w8[4], w8[6], false, false);
    u32x2 r57 = __builtin_amdgcn_permlane32_swap(w8[5], w8[7], false, false);
    union { short8 s8; u32 u[4]; } f0, f1;
    f0.u[0] = r02[0]; f0.u[1] = r13[0]; f0.u[2] = r02[1]; f0.u[3] = r13[1];
    f1.u[0] = r46[0]; f1.u[1] = r57[0]; f1.u[2] = r46[1]; f1.u[3] = r57[1];
    const int d0 = l31, d1 = 32 + l31;
    const int sw = (l31 & 7);
    __builtin_amdgcn_s_setprio(1);
#pragma unroll
    for (int kc = 0; kc < 2; kc++) {
      int grp = c * 4 + kc * 2 + hl;
      short8 v0 = *(const short8*)&Vts[d0 * 128 + ((grp ^ sw) * 8)];
      short8 v1 = *(const short8*)&Vts[d1 * 128 + ((grp ^ sw) * 8)];
      const short8 pf = kc ? f1.s8 : f0.s8;
      O0 = __builtin_amdgcn_mfma_f32_32x32x16_bf16(v0, pf, O0, 0, 0, 0);
      O1 = __builtin_amdgcn_mfma_f32_32x32x16_bf16(v1, pf, O1, 0, 0, 0);
    }
    __builtin_amdgcn_s_setprio(0);
  }
}

__global__ __launch_bounds__(256, 2) void attn_mfma(
    const u16* __restrict__ Qb, const u16* __restrict__ Kb,
    const u16* __restrict__ Vtb, u16* __restrict__ Yb) {
  __shared__ __attribute__((aligned(16))) u16 Ks[2][128 * 64];   // 32 KB
  __shared__ __attribute__((aligned(16))) u16 Vts[2][64 * 128];  // 32 KB

  int bid = blockIdx.x;
  int bh = bid & 7;
  int qt32 = bid >> 3;
  int hkv = bh & 3;
  int b = bh >> 2;
  int q0 = qt32 * 32;
  int tid = threadIdx.x;
  int g = tid >> 6;
  int lane = tid & 63;
  int l31 = lane & 31;
  int hl = lane >> 5;

  short8 QB[4];
  {
    const u16* qb =
        Qb + ((long)((bh * 4 + g) * Tq + q0 + l31)) * 64 + hl * 8;
#pragma unroll
    for (int s = 0; s < 4; s++) QB[s] = *(const short8*)(qb + s * 16);
  }

  f32x16 O0, O1;
#pragma unroll
  for (int i = 0; i < 16; i++) { O0[i] = 0.f; O1[i] = 0.f; }
  float lsum = 0.f;

  int lo = q0 - (WSq - 1);
  int st = (lo < 0 ? 0 : lo) >> 7;
  int et = (q0 + 31) >> 7;

  const u16* Kbase = Kb + ((long)bh * Tq) * 64;
  const u16* Vbase = Vtb + ((long)bh * 64) * Tq;

  int rowoffK[4], rowoffV[4];
#pragma unroll
  for (int i = 0; i < 4; i++) {
    int s = i * 256 + tid;
    int kr = s >> 3, kgp = s & 7;
    rowoffK[i] = kr * 64 + (kgp ^ (kr & 7)) * 8;
    int d = s >> 4, vgp = s & 15;
    rowoffV[i] = d * Tq + (vgp ^ (d & 7)) * 8;
  }

  {
    int k0 = st << 7;
#pragma unroll
    for (int i = 0; i < 4; i++) {
      gl_lds16(Kbase + (long)k0 * 64 + rowoffK[i], &Ks[0][(i * 256 + g * 64) * 8]);
      gl_lds16(Vbase + k0 + rowoffV[i], &Vts[0][(i * 256 + g * 64) * 8]);
    }
  }
  __syncthreads();

  int cur = 0;
  for (int kt = st; kt <= et; kt++) {
    int k0 = kt << 7;
    if (kt < et) {
      int k0n = k0 + 128;
#pragma unroll
      for (int i = 0; i < 4; i++) {
        gl_lds16(Kbase + (long)k0n * 64 + rowoffK[i],
                 &Ks[cur ^ 1][(i * 256 + g * 64) * 8]);
        gl_lds16(Vbase + k0n + rowoffV[i],
                 &Vts[cur ^ 1][(i * 256 + g * 64) * 8]);
      }
    }
    bool needC = (k0 + 127 > q0);
    bool needW = (k0 < q0 - 992);
    if (needC || needW) {
      attn_tile32<true>(k0, q0, l31, hl, Ks[cur], Vts[cur], QB, O0, O1, lsum);
    } else {
      attn_tile32<false>(k0, q0, l31, hl, Ks[cur], Vts[cur], QB, O0, O1, lsum);
    }
    __syncthreads();
    cur ^= 1;
  }

  lsum += __shfl_xor(lsum, 32);
  float invl = 1.f / lsum;

  int h = hkv * 4 + g;
  u16* yrow = Yb + ((long)(b * Tq + q0 + l31)) * 1024 + h * 64;
#pragma unroll
  for (int g4 = 0; g4 < 4; g4++) {
    union { short4 v; u16 u[4]; } pk0, pk1;
#pragma unroll
    for (int i = 0; i < 4; i++) {
      pk0.u[i] = f2bf(O0[g4 * 4 + i] * invl);
      pk1.u[i] = f2bf(O1[g4 * 4 + i] * invl);
    }
    int dA = 8 * g4 + 4 * hl;
    *(short4*)(yrow + dA) = pk0.v;
    *(short4*)(yrow + 32 + dA) = pk1.v;
  }
}

// ---------------------------------------------------------------------------
extern "C" void kernel_launch(void* const* d_in, const int* in_sizes, int n_in,
                              void* d_out, int out_size, void* d_ws,
                              size_t ws_size, hipStream_t stream) {
  const float* x     = (const float*)d_in[0];
  const float* ve    = (const float*)d_in[1];
  const float* cosp  = (const float*)d_in[2];
  const float* sinp  = (const float*)d_in[3];
  const float* Wq    = (const float*)d_in[4];
  const float* Wk    = (const float*)d_in[5];
  const float* Wv    = (const float*)d_in[6];
  const float* Wproj = (const float*)d_in[7];
  const float* Wg    = (const float*)d_in[8];

  // workspace layout (~26.3 MB):
  //  [ 0        ,  8,388,608)  xb bf16  -> Yb bf16 (xb dead after qkv gemm)
  //  [ 8,388,608, 11,534,336)  WqkvT bf16
  //  [11,534,336, 13,631,488)  WprojT bf16
  //  [13,631,488, 22,020,096)  Qb bf16
  //  [22,020,096, 24,117,248)  Kb bf16
  //  [24,117,248, 26,214,400)  Vtb bf16
  //  [26,214,400, 26,279,936)  gate f32 [4096][4]
  char* base = (char*)d_ws;
  u16* xb      = (u16*)(base);
  u16* Yb      = xb;
  u16* WqkvT   = (u16*)(base + 8388608);
  u16* WprojT  = (u16*)(base + 11534336);
  u16* Qb      = (u16*)(base + 13631488);
  u16* Kb      = (u16*)(base + 22020096);
  u16* Vtb     = (u16*)(base + 24117248);
  float* gateb = (float*)(base + 26214400);
  float* out   = (float*)d_out;

  prep<<<2752, 256, 0, stream>>>(x, xb, Wq, Wk, Wv, Wproj, Wg, WqkvT, WprojT,
                                 gateb);
  qkv_gemm_fused<<<dim3(12, 32), 256, 0, stream>>>(xb, WqkvT, ve, cosp, sinp,
                                                   gateb, Qb, Kb, Vtb);
  attn_mfma<<<512, 256, 0, stream>>>(Qb, Kb, Vtb, Yb);
  gemm_proj<<<dim3(8, 32), 256, 0, stream>>>(Yb, WprojT, out, 4096, 1024, 1024);
}

// Round 8
// 161.899 us; speedup vs baseline: 3.7847x; 1.0677x over previous
//
#include <hip/hip_runtime.h>
#include <hip/hip_bf16.h>

// Problem constants
#define Bq 2
#define Tq 2048
#define Cq 1024
#define Hq 16
#define HKVq 4
#define HDq 64
#define Gq 4
#define WSq 1024
#define GATE_CHq 32

typedef __attribute__((ext_vector_type(8))) short short8;   // 8 bf16 (4 VGPRs)
typedef __attribute__((ext_vector_type(4))) float f32x4;    // MFMA C/D frag
typedef __attribute__((ext_vector_type(16))) float f32x16;  // 32x32 MFMA C/D
typedef __attribute__((ext_vector_type(2))) unsigned int u32x2;
typedef unsigned int u32;
typedef unsigned short u16;

#if __has_builtin(__builtin_amdgcn_exp2f)
#define EXP2(x) __builtin_amdgcn_exp2f(x)
#else
#define EXP2(x) exp2f(x)
#endif

__device__ __forceinline__ u16 f2bf(float f) {
  u32 u = __float_as_uint(f);
  u32 r = (u + 0x7FFFu + ((u >> 16) & 1u)) >> 16;  // RNE
  return (u16)r;
}

__device__ __forceinline__ void gl_lds16(const u16* g, u16* l) {
  __builtin_amdgcn_global_load_lds(
      (const u32 __attribute__((address_space(1)))*)g,
      (u32 __attribute__((address_space(3)))*)l, 16, 0, 0);
}

// ---------------------------------------------------------------------------
// Fused QKV GEMM + RoPE/RMSNorm/gate epilogue.  (R0-best geometry)
// C-tile 64x128 over A[4096][1024] @ WqkvT[1536][1024]^T, BK=64.
// grid (12, 64) = 768 blocks (3 blocks/CU — max machine fill at this size).
// bx 0..7: Q; 8..9: K; 10..11: V.
// ---------------------------------------------------------------------------
__global__ __launch_bounds__(256) void qkv_gemm_fused(
    const u16* __restrict__ A, const u16* __restrict__ Bt,
    const float* __restrict__ ve, const float* __restrict__ cosp,
    const float* __restrict__ sinp, const float* __restrict__ gatebuf,
    u16* __restrict__ Qb, u16* __restrict__ Kb, u16* __restrict__ Vtb) {
  __shared__ __attribute__((aligned(16))) u16 As[64 * 64];    // 8 KB
  __shared__ __attribute__((aligned(16))) u16 Bs[128 * 64];   // 16 KB

  const int bx = blockIdx.x;
  const int bm0 = blockIdx.y * 64, bn0 = bx * 128;
  const int tid = threadIdx.x;
  const int w = tid >> 6, lane = tid & 63;
  const int wm = (w >> 1) * 32, wn = (w & 1) * 64;
  const int quad = lane >> 4, l16 = lane & 15;
  const int K = 1024;

  f32x4 acc[2][4];
#pragma unroll
  for (int mt = 0; mt < 2; mt++)
#pragma unroll
    for (int nt = 0; nt < 4; nt++) acc[mt][nt] = (f32x4){0.f, 0.f, 0.f, 0.f};

  int goffA[2], goffB[4];
#pragma unroll
  for (int i = 0; i < 2; i++) {
    int s = i * 256 + tid;
    int m = s >> 3, gp = s & 7;
    goffA[i] = m * K + (gp ^ (m & 7)) * 8;
  }
#pragma unroll
  for (int i = 0; i < 4; i++) {
    int s = i * 256 + tid;
    int m = s >> 3, gp = s & 7;
    goffB[i] = m * K + (gp ^ (m & 7)) * 8;
  }
  const u16* Ab = A + (long)bm0 * K;
  const u16* Bb = Bt + (long)bn0 * K;

  for (int k0 = 0; k0 < K; k0 += 64) {
    __syncthreads();
#pragma unroll
    for (int i = 0; i < 2; i++)
      gl_lds16(Ab + goffA[i] + k0, &As[(i * 256 + w * 64) * 8]);
#pragma unroll
    for (int i = 0; i < 4; i++)
      gl_lds16(Bb + goffB[i] + k0, &Bs[(i * 256 + w * 64) * 8]);
    __syncthreads();

#pragma unroll
    for (int ks = 0; ks < 2; ks++) {
      short8 af[2], bf[4];
#pragma unroll
      for (int mt = 0; mt < 2; mt++) {
        int ml = wm + mt * 16 + l16;
        af[mt] = *(const short8*)&As[ml * 64 + (((ks * 4 + quad) ^ (ml & 7)) * 8)];
      }
#pragma unroll
      for (int nt = 0; nt < 4; nt++) {
        int nl = wn + nt * 16 + l16;
        bf[nt] = *(const short8*)&Bs[nl * 64 + (((ks * 4 + quad) ^ (nl & 7)) * 8)];
      }
#pragma unroll
      for (int mt = 0; mt < 2; mt++)
#pragma unroll
        for (int nt = 0; nt < 4; nt++)
          acc[mt][nt] = __builtin_amdgcn_mfma_f32_16x16x32_bf16(
              af[mt], bf[nt], acc[mt][nt], 0, 0, 0);
    }
  }

  // ---- fused epilogue ----
  const int b = bm0 >> 11;                 // batch
  const int tseq0 = (bm0 & 2047) + wm;     // sequence-local t base of this wave

  if (bx < 10) {
    // Q (bx<8) or K: RoPE + RMSNorm, bf16 store in attention layout.
    u16* Dst;
    if (bx < 8) {
      int hh = bx * 2 + (w & 1);           // global q-head
      int hkv = hh >> 2, g = hh & 3;
      Dst = Qb + ((long)((b * 4 + hkv) * 4 + g) * Tq) * 64;
    } else {
      int kk = (bx - 8) * 2 + (w & 1);     // kv head
      Dst = Kb + ((long)(b * 4 + kk) * Tq) * 64;
    }
#pragma unroll
    for (int mt = 0; mt < 2; mt++) {
#pragma unroll
      for (int r = 0; r < 4; r++) {
        int t = tseq0 + mt * 16 + quad * 4 + r;
        float c0 = cosp[t * 32 + l16];
        float s0 = sinp[t * 32 + l16];
        float c1 = cosp[t * 32 + 16 + l16];
        float s1 = sinp[t * 32 + 16 + l16];
        float a0 = acc[mt][0][r], a1 = acc[mt][1][r];
        float a2 = acc[mt][2][r], a3 = acc[mt][3][r];
        float rp0 = a0 * c0 + a2 * s0;
        float rp1 = a1 * c1 + a3 * s1;
        float rp2 = a2 * c0 - a0 * s0;
        float rp3 = a3 * c1 - a1 * s1;
        float ss = rp0 * rp0 + rp1 * rp1 + rp2 * rp2 + rp3 * rp3;
        ss += __shfl_xor(ss, 1);
        ss += __shfl_xor(ss, 2);
        ss += __shfl_xor(ss, 4);
        ss += __shfl_xor(ss, 8);
        float sc = rsqrtf(ss * (1.f / 64.f) + 1.1920928955078125e-07f);
        u16* drow = Dst + (long)t * 64;
        drow[l16] = f2bf(rp0 * sc);
        drow[16 + l16] = f2bf(rp1 * sc);
        drow[32 + l16] = f2bf(rp2 * sc);
        drow[48 + l16] = f2bf(rp3 * sc);
      }
    }
  } else {
    // V: val = acc + gate(b,t,kk) * ve[b,t,kk,d]; store transposed bf16.
    int kk = (bx - 10) * 2 + (w & 1);
    u16* Dst = Vtb + ((long)(b * 4 + kk) * 64) * Tq;
#pragma unroll
    for (int mt = 0; mt < 2; mt++) {
      float vals[4][4];  // [nt][r]
#pragma unroll
      for (int r = 0; r < 4; r++) {
        int t = tseq0 + mt * 16 + quad * 4 + r;
        long bt = (long)b * Tq + t;
        float gv = gatebuf[bt * 4 + kk];
        const float* verow = ve + bt * 256 + kk * 64;
#pragma unroll
        for (int nt = 0; nt < 4; nt++)
          vals[nt][r] = acc[mt][nt][r] + gv * verow[nt * 16 + l16];
      }
      int t0m = tseq0 + mt * 16 + quad * 4;
#pragma unroll
      for (int nt = 0; nt < 4; nt++) {
        int d = nt * 16 + l16;
        union { short4 v; u16 u[4]; } p;
#pragma unroll
        for (int r = 0; r < 4; r++) p.u[r] = f2bf(vals[nt][r]);
        *(short4*)(Dst + (long)d * Tq + t0m) = p.v;
      }
    }
  }
}

// ---------------------------------------------------------------------------
// proj GEMM (f32 out), 64x128 tile, BK=64 — R0-best geometry. grid (8, 64).
// ---------------------------------------------------------------------------
__global__ __launch_bounds__(256) void gemm_proj(
    const u16* __restrict__ A, const u16* __restrict__ Bt,
    float* __restrict__ C, int M, int N, int K) {
  __shared__ __attribute__((aligned(16))) u16 As[64 * 64];
  __shared__ __attribute__((aligned(16))) u16 Bs[128 * 64];

  const int bm0 = blockIdx.y * 64, bn0 = blockIdx.x * 128;
  const int tid = threadIdx.x;
  const int w = tid >> 6, lane = tid & 63;
  const int wm = (w >> 1) * 32, wn = (w & 1) * 64;
  const int quad = lane >> 4, l16 = lane & 15;

  f32x4 acc[2][4];
#pragma unroll
  for (int mt = 0; mt < 2; mt++)
#pragma unroll
    for (int nt = 0; nt < 4; nt++) acc[mt][nt] = (f32x4){0.f, 0.f, 0.f, 0.f};

  int goffA[2], goffB[4];
#pragma unroll
  for (int i = 0; i < 2; i++) {
    int s = i * 256 + tid;
    int m = s >> 3, gp = s & 7;
    goffA[i] = m * K + (gp ^ (m & 7)) * 8;
  }
#pragma unroll
  for (int i = 0; i < 4; i++) {
    int s = i * 256 + tid;
    int m = s >> 3, gp = s & 7;
    goffB[i] = m * K + (gp ^ (m & 7)) * 8;
  }
  const u16* Ab = A + (long)bm0 * K;
  const u16* Bb = Bt + (long)bn0 * K;

  for (int k0 = 0; k0 < K; k0 += 64) {
    __syncthreads();
#pragma unroll
    for (int i = 0; i < 2; i++)
      gl_lds16(Ab + goffA[i] + k0, &As[(i * 256 + w * 64) * 8]);
#pragma unroll
    for (int i = 0; i < 4; i++)
      gl_lds16(Bb + goffB[i] + k0, &Bs[(i * 256 + w * 64) * 8]);
    __syncthreads();

#pragma unroll
    for (int ks = 0; ks < 2; ks++) {
      short8 af[2], bf[4];
#pragma unroll
      for (int mt = 0; mt < 2; mt++) {
        int ml = wm + mt * 16 + l16;
        af[mt] = *(const short8*)&As[ml * 64 + (((ks * 4 + quad) ^ (ml & 7)) * 8)];
      }
#pragma unroll
      for (int nt = 0; nt < 4; nt++) {
        int nl = wn + nt * 16 + l16;
        bf[nt] = *(const short8*)&Bs[nl * 64 + (((ks * 4 + quad) ^ (nl & 7)) * 8)];
      }
#pragma unroll
      for (int mt = 0; mt < 2; mt++)
#pragma unroll
        for (int nt = 0; nt < 4; nt++)
          acc[mt][nt] = __builtin_amdgcn_mfma_f32_16x16x32_bf16(
              af[mt], bf[nt], acc[mt][nt], 0, 0, 0);
    }
  }

#pragma unroll
  for (int mt = 0; mt < 2; mt++)
#pragma unroll
    for (int nt = 0; nt < 4; nt++) {
      int row0 = bm0 + wm + mt * 16 + quad * 4;
      int col = bn0 + wn + nt * 16 + l16;
#pragma unroll
      for (int r = 0; r < 4; r++)
        C[(long)(row0 + r) * N + col] = acc[mt][nt][r];
    }
}

// ---------------------------------------------------------------------------
// prep (consolidated: 1216 blocks instead of 2752 — launch-ramp reduction).
// bx 0..511: x->bf16, grid-stride 4 chunks each.
// bx 512..1151: weight transposes.  bx 1152..1215: gate.
// ---------------------------------------------------------------------------
__global__ __launch_bounds__(256) void prep(
    const float* __restrict__ x, u16* __restrict__ xb,
    const float* __restrict__ Wq, const float* __restrict__ Wk,
    const float* __restrict__ Wv, const float* __restrict__ Wproj,
    const float* __restrict__ Wg, u16* __restrict__ Dqkv,
    u16* __restrict__ Dproj, float* __restrict__ gatebuf) {
  __shared__ float tile[64][65];
  int bx = blockIdx.x;
  int tid = threadIdx.x;
  if (bx < 512) {
#pragma unroll
    for (int c = 0; c < 4; c++) {
      int i = ((bx + c * 512) * 256 + tid) * 8;
      float4 a = *(const float4*)(x + i);
      float4 b = *(const float4*)(x + i + 4);
      union { short8 v; u16 u[8]; } o;
      o.u[0] = f2bf(a.x); o.u[1] = f2bf(a.y); o.u[2] = f2bf(a.z); o.u[3] = f2bf(a.w);
      o.u[4] = f2bf(b.x); o.u[5] = f2bf(b.y); o.u[6] = f2bf(b.z); o.u[7] = f2bf(b.w);
      *(short8*)(xb + i) = o.v;
    }
    return;
  }
  if (bx >= 1152) {
    int p = (bx - 1152) * 256 + tid;   // 0..16383
    int bt = p >> 2, kk = p & 3;
    const float* xr = x + (long)bt * Cq;
    float dot = 0.f;
#pragma unroll
    for (int i = 0; i < GATE_CHq; i++) dot += xr[i] * Wg[i * HKVq + kk];
    gatebuf[p] = 2.f / (1.f + expf(-dot));
    return;
  }
  int wb = bx - 512;              // 0..639
  int obx = wb >> 4;              // 0..39
  int k0 = (wb & 15) * 64;
  const float* S;
  u16* Dst;
  int N, nb;
  if (obx < 16)      { S = Wq;    N = 1024; nb = obx;      Dst = Dqkv; }
  else if (obx < 20) { S = Wk;    N = 256;  nb = obx - 16; Dst = Dqkv + 1024 * 1024; }
  else if (obx < 24) { S = Wv;    N = 256;  nb = obx - 20; Dst = Dqkv + 1280 * 1024; }
  else               { S = Wproj; N = 1024; nb = obx - 24; Dst = Dproj; }
  int n0 = nb * 64;
#pragma unroll
  for (int i = 0; i < 16; i++) {
    int idx = i * 256 + tid;
    int kl = idx >> 6, nl = idx & 63;
    tile[kl][nl] = S[(long)(k0 + kl) * N + n0 + nl];
  }
  __syncthreads();
#pragma unroll
  for (int i = 0; i < 16; i++) {
    int idx = i * 256 + tid;
    int nl = idx >> 6, kl = idx & 63;
    Dst[(long)(n0 + nl) * 1024 + k0 + kl] = f2bf(tile[kl][nl]);
  }
}

// ---------------------------------------------------------------------------
// MFMA flash attention v5c: 32x32x16 MFMA, swapped operands both ways.
// S^T = K·Q^T; P packed+permlane32_swap in-register; O^T = V^T·P^T.
// K/V double-buffered; prefetch before compute; one barrier per tile.
// ---------------------------------------------------------------------------
#define CEXP 0.18033688011112042f   // 0.125 * log2(e)
#define CEXP8 1.4426950408889634f   // 8 * 0.125 * log2(e)

template <bool MASK>
__device__ __forceinline__ void attn_tile32(
    int k0, int q0, int l31, int hl, const u16* __restrict__ Ks,
    const u16* __restrict__ Vts, const short8 (&QB)[4], f32x16& O0, f32x16& O1,
    float& lsum) {
  const int qpos = q0 + l31;
#pragma unroll
  for (int c = 0; c < 4; c++) {
    const int key = c * 32 + l31;
    f32x16 S;
#pragma unroll
    for (int i = 0; i < 16; i++) S[i] = 0.f;
    __builtin_amdgcn_s_setprio(1);
#pragma unroll
    for (int s = 0; s < 4; s++) {
      short8 kf = *(const short8*)&Ks[key * 64 + (((s * 2 + hl) ^ (key & 7)) * 8)];
      S = __builtin_amdgcn_mfma_f32_32x32x16_bf16(kf, QB[s], S, 0, 0, 0);
    }
    __builtin_amdgcn_s_setprio(0);
    const int kb = k0 + c * 32 + 4 * hl;
    float p[16];
    float la0 = 0.f, la1 = 0.f;
#pragma unroll
    for (int r = 0; r < 16; r++) {
      float sv = S[r];
      if (MASK) {
        int kpos = kb + (r & 3) + 8 * (r >> 2);
        u32 diff = (u32)(qpos - kpos);
        sv = (diff < (u32)WSq) ? sv : -1e30f;
      }
      float pv = EXP2(__builtin_fmaf(sv, CEXP, -CEXP8));
      if (r & 1) la1 += pv; else la0 += pv;
      p[r] = pv;
    }
    lsum += la0 + la1;
    u32 w8[8];
#pragma unroll
    for (int i = 0; i < 8; i++) {
      u32 lo = __float_as_uint(p[2 * i]) + 0x8000u;
      u32 hi = __float_as_uint(p[2 * i + 1]) + 0x8000u;
      w8[i] = __builtin_amdgcn_perm(hi, lo, 0x07060302u);
    }
    u32x2 r02 = __builtin_amdgcn_permlane32_swap(w8[0], w8[2], false, false);
    u32x2 r13 = __builtin_amdgcn_permlane32_swap(w8[1], w8[3], false, false);
    u32x2 r46 = __builtin_amdgcn_permlane32_swap(w8[4], w8[6], false, false);
    u32x2 r57 = __builtin_amdgcn_permlane32_swap(w8[5], w8[7], false, false);
    union { short8 s8; u32 u[4]; } f0, f1;
    f0.u[0] = r02[0]; f0.u[1] = r13[0]; f0.u[2] = r02[1]; f0.u[3] = r13[1];
    f1.u[0] = r46[0]; f1.u[1] = r57[0]; f1.u[2] = r46[1]; f1.u[3] = r57[1];
    const int d0 = l31, d1 = 32 + l31;
    const int sw = (l31 & 7);
    __builtin_amdgcn_s_setprio(1);
#pragma unroll
    for (int kc = 0; kc < 2; kc++) {
      int grp = c * 4 + kc * 2 + hl;
      short8 v0 = *(const short8*)&Vts[d0 * 128 + ((grp ^ sw) * 8)];
      short8 v1 = *(const short8*)&Vts[d1 * 128 + ((grp ^ sw) * 8)];
      const short8 pf = kc ? f1.s8 : f0.s8;
      O0 = __builtin_amdgcn_mfma_f32_32x32x16_bf16(v0, pf, O0, 0, 0, 0);
      O1 = __builtin_amdgcn_mfma_f32_32x32x16_bf16(v1, pf, O1, 0, 0, 0);
    }
    __builtin_amdgcn_s_setprio(0);
  }
}

__global__ __launch_bounds__(256, 2) void attn_mfma(
    const u16* __restrict__ Qb, const u16* __restrict__ Kb,
    const u16* __restrict__ Vtb, u16* __restrict__ Yb) {
  __shared__ __attribute__((aligned(16))) u16 Ks[2][128 * 64];   // 32 KB
  __shared__ __attribute__((aligned(16))) u16 Vts[2][64 * 128];  // 32 KB

  int bid = blockIdx.x;
  int bh = bid & 7;
  int qt32 = bid >> 3;
  int hkv = bh & 3;
  int b = bh >> 2;
  int q0 = qt32 * 32;
  int tid = threadIdx.x;
  int g = tid >> 6;
  int lane = tid & 63;
  int l31 = lane & 31;
  int hl = lane >> 5;

  short8 QB[4];
  {
    const u16* qb =
        Qb + ((long)((bh * 4 + g) * Tq + q0 + l31)) * 64 + hl * 8;
#pragma unroll
    for (int s = 0; s < 4; s++) QB[s] = *(const short8*)(qb + s * 16);
  }

  f32x16 O0, O1;
#pragma unroll
  for (int i = 0; i < 16; i++) { O0[i] = 0.f; O1[i] = 0.f; }
  float lsum = 0.f;

  int lo = q0 - (WSq - 1);
  int st = (lo < 0 ? 0 : lo) >> 7;
  int et = (q0 + 31) >> 7;

  const u16* Kbase = Kb + ((long)bh * Tq) * 64;
  const u16* Vbase = Vtb + ((long)bh * 64) * Tq;

  int rowoffK[4], rowoffV[4];
#pragma unroll
  for (int i = 0; i < 4; i++) {
    int s = i * 256 + tid;
    int kr = s >> 3, kgp = s & 7;
    rowoffK[i] = kr * 64 + (kgp ^ (kr & 7)) * 8;
    int d = s >> 4, vgp = s & 15;
    rowoffV[i] = d * Tq + (vgp ^ (d & 7)) * 8;
  }

  {
    int k0 = st << 7;
#pragma unroll
    for (int i = 0; i < 4; i++) {
      gl_lds16(Kbase + (long)k0 * 64 + rowoffK[i], &Ks[0][(i * 256 + g * 64) * 8]);
      gl_lds16(Vbase + k0 + rowoffV[i], &Vts[0][(i * 256 + g * 64) * 8]);
    }
  }
  __syncthreads();

  int cur = 0;
  for (int kt = st; kt <= et; kt++) {
    int k0 = kt << 7;
    if (kt < et) {
      int k0n = k0 + 128;
#pragma unroll
      for (int i = 0; i < 4; i++) {
        gl_lds16(Kbase + (long)k0n * 64 + rowoffK[i],
                 &Ks[cur ^ 1][(i * 256 + g * 64) * 8]);
        gl_lds16(Vbase + k0n + rowoffV[i],
                 &Vts[cur ^ 1][(i * 256 + g * 64) * 8]);
      }
    }
    bool needC = (k0 + 127 > q0);
    bool needW = (k0 < q0 - 992);
    if (needC || needW) {
      attn_tile32<true>(k0, q0, l31, hl, Ks[cur], Vts[cur], QB, O0, O1, lsum);
    } else {
      attn_tile32<false>(k0, q0, l31, hl, Ks[cur], Vts[cur], QB, O0, O1, lsum);
    }
    __syncthreads();
    cur ^= 1;
  }

  lsum += __shfl_xor(lsum, 32);
  float invl = 1.f / lsum;

  int h = hkv * 4 + g;
  u16* yrow = Yb + ((long)(b * Tq + q0 + l31)) * 1024 + h * 64;
#pragma unroll
  for (int g4 = 0; g4 < 4; g4++) {
    union { short4 v; u16 u[4]; } pk0, pk1;
#pragma unroll
    for (int i = 0; i < 4; i++) {
      pk0.u[i] = f2bf(O0[g4 * 4 + i] * invl);
      pk1.u[i] = f2bf(O1[g4 * 4 + i] * invl);
    }
    int dA = 8 * g4 + 4 * hl;
    *(short4*)(yrow + dA) = pk0.v;
    *(short4*)(yrow + 32 + dA) = pk1.v;
  }
}

// ---------------------------------------------------------------------------
extern "C" void kernel_launch(void* const* d_in, const int* in_sizes, int n_in,
                              void* d_out, int out_size, void* d_ws,
                              size_t ws_size, hipStream_t stream) {
  const float* x     = (const float*)d_in[0];
  const float* ve    = (const float*)d_in[1];
  const float* cosp  = (const float*)d_in[2];
  const float* sinp  = (const float*)d_in[3];
  const float* Wq    = (const float*)d_in[4];
  const float* Wk    = (const float*)d_in[5];
  const float* Wv    = (const float*)d_in[6];
  const float* Wproj = (const float*)d_in[7];
  const float* Wg    = (const float*)d_in[8];

  // workspace layout (~26.3 MB):
  //  [ 0        ,  8,388,608)  xb bf16  -> Yb bf16 (xb dead after qkv gemm)
  //  [ 8,388,608, 11,534,336)  WqkvT bf16
  //  [11,534,336, 13,631,488)  WprojT bf16
  //  [13,631,488, 22,020,096)  Qb bf16
  //  [22,020,096, 24,117,248)  Kb bf16
  //  [24,117,248, 26,214,400)  Vtb bf16
  //  [26,214,400, 26,279,936)  gate f32 [4096][4]
  char* base = (char*)d_ws;
  u16* xb      = (u16*)(base);
  u16* Yb      = xb;
  u16* WqkvT   = (u16*)(base + 8388608);
  u16* WprojT  = (u16*)(base + 11534336);
  u16* Qb      = (u16*)(base + 13631488);
  u16* Kb      = (u16*)(base + 22020096);
  u16* Vtb     = (u16*)(base + 24117248);
  float* gateb = (float*)(base + 26214400);
  float* out   = (float*)d_out;

  prep<<<1216, 256, 0, stream>>>(x, xb, Wq, Wk, Wv, Wproj, Wg, WqkvT, WprojT,
                                 gateb);
  qkv_gemm_fused<<<dim3(12, 64), 256, 0, stream>>>(xb, WqkvT, ve, cosp, sinp,
                                                   gateb, Qb, Kb, Vtb);
  attn_mfma<<<512, 256, 0, stream>>>(Qb, Kb, Vtb, Yb);
  gemm_proj<<<dim3(8, 64), 256, 0, stream>>>(Yb, WprojT, out, 4096, 1024, 1024);
}